// Round 1
// baseline (2553.193 us; speedup 1.0000x reference)
//
#include <hip/hip_runtime.h>
#include <stdint.h>

#define BB 8
#define RR 2048
#define CC 4096
#define KFRONT 1228   // int(4096*0.30)
#define KRAND  409    // int(4096*0.10)
#define NT 256
#define ROWS 16       // input rows per block (= 32-wide u-stripe)
#define RPW 4         // rows per wave (ROWS / 4 waves)

// ---------------- threefry2x32 (JAX), key=(0,42), ctr=(0,i) ----------------
__device__ __forceinline__ uint32_t rotl32(uint32_t x, uint32_t r) {
  return (x << r) | (x >> (32u - r));
}

__device__ __forceinline__ uint32_t threefry_bits(uint32_t i) {
  const uint32_t ks0 = 0u, ks1 = 42u;
  const uint32_t ks2 = 0x1BD11BDAu ^ ks0 ^ ks1;
  uint32_t x0 = ks0;        // ctr_hi (=0) + ks0
  uint32_t x1 = i + ks1;    // ctr_lo + ks1
#define R4(a, b, c, d)                         \
  x0 += x1; x1 = rotl32(x1, (a)); x1 ^= x0;    \
  x0 += x1; x1 = rotl32(x1, (b)); x1 ^= x0;    \
  x0 += x1; x1 = rotl32(x1, (c)); x1 ^= x0;    \
  x0 += x1; x1 = rotl32(x1, (d)); x1 ^= x0;
  R4(13u, 15u, 26u, 6u)  x0 += ks1; x1 += ks2 + 1u;
  R4(17u, 29u, 16u, 24u) x0 += ks2; x1 += ks0 + 2u;
  R4(13u, 15u, 26u, 6u)  x0 += ks0; x1 += ks1 + 3u;
  R4(17u, 29u, 16u, 24u) x0 += ks1; x1 += ks2 + 4u;
  R4(13u, 15u, 26u, 6u)  x0 += ks2; x1 += ks0 + 5u;
#undef R4
  return x0 ^ x1;
}

// ---------------- wave-level exact k-th smallest -----------------------------
// Elements: composite ((u64)key[j] << 12) | (j*64 + lane), 64 per lane, one
// row (4096 distinct composites) per wave. MSB-first 8-bit radix with a
// private per-wave LDS histogram (no barriers, wave-internal DS ordering),
// per-lane byte-counter aggregation on the first (<=16 bin) pass, and early
// termination when the k-th element is uniquely determined.
template <int NPASS, int NB1>
__device__ __forceinline__ uint64_t wave_select(const uint32_t (&key)[64],
                                                int lane, int k,
                                                uint32_t* hist) {
  uint64_t prefix = 0;
  uint64_t result = 0;
  int kk = k;

  // Scan the 256-bin histogram, pick the digit, update (prefix, kk).
  // Returns true when the k-th composite is fully resolved (in `result`).
  auto pick = [&](int shift) -> bool {
    const uint4 h = *(const uint4*)(hist + 4 * lane);
    int s0 = (int)h.x, s1 = s0 + (int)h.y, s2 = s1 + (int)h.z,
        s3 = s2 + (int)h.w;
    int inc = s3;
#pragma unroll
    for (int off = 1; off < 64; off <<= 1) {
      int v = __shfl_up(inc, (unsigned)off);
      if (lane >= off) inc += v;
    }
    const int base = inc - s3;  // exclusive prefix over lanes (4 bins/lane)
    const uint64_t bal = __ballot(base + s3 >= kk);
    const int L = __ffsll((unsigned long long)bal) - 1;
    const int bL = __shfl(base, L);
    const int a0 = __shfl(s0, L), a1 = __shfl(s1, L), a2 = __shfl(s2, L),
              a3 = __shfl(s3, L);
    int dsub, below, cnt;
    if (kk <= bL + a0)      { dsub = 0; below = bL;      cnt = a0;      }
    else if (kk <= bL + a1) { dsub = 1; below = bL + a0; cnt = a1 - a0; }
    else if (kk <= bL + a2) { dsub = 2; below = bL + a1; cnt = a2 - a1; }
    else                    { dsub = 3; below = bL + a2; cnt = a3 - a2; }
    prefix = (prefix << 8) | (uint32_t)(4 * L + dsub);
    kk -= below;
    if (shift == 0) { result = prefix; return true; }  // full composite known
    if (cnt == 1 || kk == 1 || kk == cnt) {
      // k-th is the unique / min / max element matching `prefix`.
      const bool usemin = (kk == 1 && cnt > 1);
      uint64_t found = usemin ? ~0ull : 0ull;
#pragma unroll
      for (int j = 0; j < 64; ++j) {
        const uint64_t comp =
            ((uint64_t)key[j] << 12) | (uint32_t)(j * 64 + lane);
        if ((comp >> shift) == prefix)
          found = usemin ? (comp < found ? comp : found)
                         : (comp > found ? comp : found);
      }
#pragma unroll
      for (int off = 1; off < 64; off <<= 1) {
        const uint64_t o = (uint64_t)__shfl_xor((unsigned long long)found, off);
        found = usemin ? (o < found ? o : found) : (o > found ? o : found);
      }
      result = found;
      return true;
    }
    return false;
  };

  // ---- pass 1: NB1 bins, per-lane byte-counter aggregation ----
  {
    *(uint4*)(hist + 4 * lane) = make_uint4(0, 0, 0, 0);
    const int ksh = 8 * NPASS - 20;  // comp>>(8*(NPASS-1)) == key>>ksh
    uint64_t c0 = 0, c1 = 0;
#pragma unroll
    for (int j = 0; j < 64; ++j) {
      const uint32_t d = key[j] >> ksh;
      if constexpr (NB1 <= 8) {
        c0 += 1ull << (8 * d);
      } else {
        if (d < 8) c0 += 1ull << (8 * d);
        else       c1 += 1ull << (8 * (d - 8));
      }
    }
#pragma unroll
    for (int b = 0; b < NB1; ++b) {
      const uint32_t cv =
          (uint32_t)(((b < 8) ? c0 : c1) >> (8 * (b & 7))) & 0xffu;
      if (cv) atomicAdd(&hist[b], cv);
    }
    if (pick(8 * (NPASS - 1))) return result;
  }
  // ---- passes 2..NPASS: predicated atomics over surviving candidates ----
#pragma unroll 1
  for (int p = NPASS - 2; p >= 0; --p) {
    const int shift = 8 * p;
    *(uint4*)(hist + 4 * lane) = make_uint4(0, 0, 0, 0);
#pragma unroll
    for (int j = 0; j < 64; ++j) {
      const uint64_t comp =
          ((uint64_t)key[j] << 12) | (uint32_t)(j * 64 + lane);
      if ((comp >> (shift + 8)) == prefix)
        atomicAdd(&hist[(uint32_t)(comp >> shift) & 255u], 1u);
    }
    if (pick(shift)) return result;
  }
  return result;  // unreachable: pick(0) always resolves
}

// ---------------- fused: select + mask-build + transpose + emit ------------
// out[b, v, u] = M[b, u>>1, ((u&1)<<11) + v]; block owns u in [u0,u0+32),
// i.e. input rows [r0, r0+16), all v. Phase 1: one wave per row, barrier-free.
__global__ __launch_bounds__(NT, 4) void fused_kernel(
    const float* __restrict__ score, float* __restrict__ outS,
    float* __restrict__ outT) {
  __shared__ __align__(16) uint32_t sh_hist[4 * 256];  // per-wave histograms
  __shared__ uint32_t zbT[128][17];  // student zero-bits, [word][row], padded
  __shared__ uint32_t fb0[128];      // front bits of global row 0 (teacher)
  __shared__ float tin[ROWS][130];   // phase-2 transpose tile (2-way banks)

  const int tid = threadIdx.x;
  const int lane = tid & 63;
  const int wv = tid >> 6;
  const int stripe = blockIdx.x;  // 0..127
  const int b = blockIdx.y;       // 0..7
  const int r0 = stripe * ROWS;
  const int u0 = 2 * r0;

  uint32_t* hist = sh_hist + wv * 256;

  // ================= Phase 1: wave-per-row exact selection ================
#pragma unroll 1
  for (int t = 0; t < RPW; ++t) {
    const int rl = wv * RPW + t;
    const int rowid = b * RR + (r0 + rl);
    const float* srow = score + (size_t)rowid * CC;
    uint32_t key[64];
    // keyS: IEEE total-order flip (ascending uint == ascending float)
#pragma unroll
    for (int j = 0; j < 64; ++j) {
      const uint32_t fb = __float_as_uint(srow[j * 64 + lane]);
      key[j] = fb ^ ((uint32_t)((int32_t)fb >> 31) | 0x80000000u);
    }
    const uint64_t pivF = wave_select<6, 16>(key, lane, KFRONT, hist);
    uint64_t fm = 0;  // per-lane front-membership bits (bit j)
#pragma unroll
    for (int j = 0; j < 64; ++j) {
      const uint64_t comp =
          ((uint64_t)key[j] << 12) | (uint32_t)(j * 64 + lane);
      fm |= (uint64_t)(comp <= pivF) << j;
    }
    if (r0 + rl == 0) {  // teacher bug: only row 0 of each batch is masked
#pragma unroll
      for (int j = 0; j < 64; ++j) {
        const uint64_t bf = __ballot((fm >> j) & 1ull);
        if ((lane & 31) == 0)
          fb0[2 * j + (lane >> 5)] =
              (lane & 32) ? (uint32_t)(bf >> 32) : (uint32_t)bf;
      }
    }
    // keyR: top 23 bits of JAX random bits (stable ties by index)
#pragma unroll
    for (int j = 0; j < 64; ++j)
      key[j] = threefry_bits((uint32_t)rowid * (uint32_t)CC +
                             (uint32_t)(j * 64 + lane)) >> 9;
    const uint64_t pivR = wave_select<5, 8>(key, lane, KRAND, hist);
#pragma unroll
    for (int j = 0; j < 64; ++j) {
      const uint64_t comp =
          ((uint64_t)key[j] << 12) | (uint32_t)(j * 64 + lane);
      const int isZ = (int)((fm >> j) & 1ull) | (int)(comp <= pivR);
      const uint64_t bz = __ballot(isZ);
      if ((lane & 31) == 0)
        zbT[2 * j + (lane >> 5)][rl] =
            (lane & 32) ? (uint32_t)(bz >> 32) : (uint32_t)bz;
    }
  }
  __syncthreads();

  // ================= Phase 2: tiled transpose + masked emit ==========
  const int ul = tid & 31;     // u_local 0..31
  const int rl2 = ul >> 1;     // local row 0..15
  const int half = ul & 1;
  const bool isrow0 = (r0 + rl2) == 0;
  float* oS = outS + (size_t)b * RR * CC + (size_t)(u0 + ul);
  float* oT = outT + (size_t)b * RR * CC + (size_t)(u0 + ul);

#pragma unroll 1
  for (int vt = 0; vt < 32; ++vt) {
    const int v0 = vt * 64;
    // stage 16 rows x 128 cols (two 64-wide halves), 256B coalesced runs
#pragma unroll
    for (int it = 0; it < 8; ++it) {
      const int idx = it * NT + tid;
      const int lrl = idx >> 7;
      const int colsel = (idx >> 6) & 1;
      const int ll = idx & 63;
      tin[lrl][colsel * 64 + ll] =
          score[(size_t)(b * RR + r0 + lrl) * CC + colsel * 2048 + v0 + ll];
    }
    __syncthreads();
    const int w0 = half * 64 + (v0 >> 5);
    const uint32_t z0 = zbT[w0][rl2], z1 = zbT[w0 + 1][rl2];
    const uint32_t f0 = fb0[w0], f1 = fb0[w0 + 1];  // dead unless isrow0
#pragma unroll
    for (int it = 0; it < 8; ++it) {
      const int vl = it * 8 + (tid >> 5);  // 0..63
      const float s = tin[rl2][half * 64 + vl];
      const uint32_t zw = (vl & 32) ? z1 : z0;
      const uint32_t fw = (vl & 32) ? f1 : f0;
      const int bit = vl & 31;
      const float st = ((zw >> bit) & 1u) ? 0.0f : s;
      const float te = isrow0 ? ((((fw >> bit) & 1u)) ? s : 0.0f) : s;
      const size_t o = (size_t)(v0 + vl) * CC;
      oS[o] = st;
      oT[o] = te;
    }
    __syncthreads();  // tin reused next iteration
  }
}

extern "C" void kernel_launch(void* const* d_in, const int* in_sizes, int n_in,
                              void* d_out, int out_size, void* d_ws,
                              size_t ws_size, hipStream_t stream) {
  const float* score = (const float*)d_in[0];
  float* outS = (float*)d_out;
  float* outT = outS + (size_t)BB * RR * CC;
  dim3 grid(RR / ROWS, BB);  // 128 x 8
  hipLaunchKernelGGL(fused_kernel, grid, dim3(NT), 0, stream, score, outS,
                     outT);
}